// Round 7
// baseline (2939.565 us; speedup 1.0000x reference)
//
#include <hip/hip_runtime.h>

#define N_NODES 50000
#define N_EDGES 800000
#define BKN 64                      // nodes per bucket: bucket = dst >> 6
#define NBUCK 782                   // ceil(50000/64)
#define ASTR 132                    // LDS acc row stride (floats): 16B-aligned + 2-way banks only
#define EPB 2048                    // edges per stripe-block (straggler-tail control)
#define NSTRIPE ((N_EDGES + EPB - 1) / EPB)  // 391

typedef __attribute__((ext_vector_type(8))) short short8;
typedef __attribute__((ext_vector_type(4))) float float4v;

__device__ inline unsigned short f2bf(float f) {
    unsigned u = __float_as_uint(f);
    unsigned r = u + 0x7fff + ((u >> 16) & 1);
    return (unsigned short)(r >> 16);
}
__device__ inline float bf2f(unsigned short h) {
    return __uint_as_float(((unsigned)h) << 16);
}

// ---------------- fused: bucket histogram (391 blocks) + weight split (288) ----------

__global__ void __launch_bounds__(256) fused_hist_prep(
    const int* __restrict__ dst, int* __restrict__ bcnt, const float* __restrict__ fcW,
    const float* __restrict__ W, const float* __restrict__ Wl, unsigned short* __restrict__ hi,
    unsigned short* __restrict__ lo) {
    int bx = blockIdx.x;
    if (bx < NSTRIPE) {
        __shared__ int lhist[1024];
        int t = threadIdx.x;
        for (int k = t; k < 1024; k += 256) lhist[k] = 0;
        __syncthreads();
        int base = bx * EPB + t;
#pragma unroll
        for (int k = 0; k < EPB / 256; k++) {
            int i = base + k * 256;
            if (i < N_EDGES) atomicAdd(&lhist[((unsigned)dst[i]) >> 6], 1);
        }
        __syncthreads();
        for (int k = t; k < NBUCK; k += 256)
            if (lhist[k]) atomicAdd(&bcnt[k], lhist[k]);
    } else {
        // weight split: [0,16384) fcW | [16384,65536) W | [65536,73728) W_last
        int i = (bx - NSTRIPE) * 256 + threadIdx.x;
        float v;
        if (i < 16384) v = fcW[i];
        else if (i < 65536) v = W[i - 16384];
        else if (i < 73728) v = Wl[i - 65536];
        else return;
        unsigned short h = f2bf(v);
        hi[i] = h;
        lo[i] = f2bf(v - bf2f(h));
    }
}

// ---------------- bucket offsets (1 block, 1024 threads) ----------------

__global__ void bucket_scan(const int* __restrict__ bcnt, int* __restrict__ boff,
                            int* __restrict__ cursor) {
    __shared__ int sm[1024];
    int t = threadIdx.x;
    int v = (t < NBUCK) ? bcnt[t] : 0;
    sm[t] = v;
    __syncthreads();
    for (int o = 1; o < 1024; o <<= 1) {
        int x = sm[t];
        int a = (t >= o) ? sm[t - o] : 0;
        __syncthreads();
        sm[t] = x + a;
        __syncthreads();
    }
    if (t < NBUCK) {
        boff[t] = sm[t] - v;
        cursor[t] = sm[t] - v;
    }
    if (t == NBUCK - 1) boff[NBUCK] = sm[t];
}

// ---------------- split-bf16 MFMA GEMM body (global A) ----------------
// D = Ahi*Whi + Alo*Whi + Ahi*Wlo (missing Alo*Wlo ~ 2^-18 rel).

template <int COLS, bool RELU, bool LAST>
__device__ __forceinline__ void gemm_body(int bx, const float* __restrict__ U,
                                          const unsigned short* __restrict__ Whi,
                                          const unsigned short* __restrict__ Wlo,
                                          const float* __restrict__ bias,
                                          unsigned short* __restrict__ hi_out,
                                          unsigned short* __restrict__ lo_out,
                                          float* __restrict__ out_last, int nrows) {
    int wave = threadIdx.x >> 6;
    int lane = threadIdx.x & 63;
    int m = lane & 15;
    int quad = lane >> 4;
    int r0 = bx * 64 + wave * 16;
    int rowA = r0 + m;
    if (rowA >= nrows) rowA = nrows - 1;  // clamp OOB loads (stores guarded)

    short8 ahi[4], alo[4];
    const float* arow = U + (size_t)rowA * 128 + quad * 8;
#pragma unroll
    for (int kc = 0; kc < 4; kc++) {
        float4 f0 = *(const float4*)(arow + kc * 32);
        float4 f1 = *(const float4*)(arow + kc * 32 + 4);
        float fv[8] = {f0.x, f0.y, f0.z, f0.w, f1.x, f1.y, f1.z, f1.w};
#pragma unroll
        for (int j = 0; j < 8; j++) {
            unsigned short h = f2bf(fv[j]);
            ahi[kc][j] = (short)h;
            alo[kc][j] = (short)f2bf(fv[j] - bf2f(h));
        }
    }

#pragma unroll
    for (int nt = 0; nt < COLS / 16; nt++) {
        int n = nt * 16 + m;
        const unsigned short* bhp = Whi + (size_t)n * 128 + quad * 8;
        const unsigned short* blp = Wlo + (size_t)n * 128 + quad * 8;
        float4v c = {0.f, 0.f, 0.f, 0.f};
#pragma unroll
        for (int kc = 0; kc < 4; kc++) {
            short8 bh = *(const short8*)(bhp + kc * 32);
            short8 bl = *(const short8*)(blp + kc * 32);
            c = __builtin_amdgcn_mfma_f32_16x16x32_bf16(ahi[kc], bh, c, 0, 0, 0);
            c = __builtin_amdgcn_mfma_f32_16x16x32_bf16(alo[kc], bh, c, 0, 0, 0);
            c = __builtin_amdgcn_mfma_f32_16x16x32_bf16(ahi[kc], bl, c, 0, 0, 0);
        }
        float bv = bias[n];
#pragma unroll
        for (int k = 0; k < 4; k++) {
            int r = r0 + quad * 4 + k;
            if (r < nrows) {
                float v = c[k] + bv;
                if (RELU) v = fmaxf(v, 0.f);
                if (LAST) {
                    out_last[(size_t)r * COLS + n] = v;
                } else {
                    unsigned short hh = f2bf(v);
                    hi_out[(size_t)r * COLS + n] = hh;
                    lo_out[(size_t)r * COLS + n] = f2bf(v - bf2f(hh));
                }
            }
        }
    }
}

// ---------------- fused: pass A binning (391 blocks) + SLP GEMM (782) ----------

__global__ void __launch_bounds__(256) fused_binA_gemm(
    const int* __restrict__ src, const int* __restrict__ dst, int* __restrict__ cursor,
    int* __restrict__ packed, const float* __restrict__ X, const unsigned short* __restrict__ whi,
    const unsigned short* __restrict__ wlo, const float* __restrict__ fcb,
    unsigned short* __restrict__ hi_out, unsigned short* __restrict__ lo_out) {
    int bx = blockIdx.x;
    if (bx < NSTRIPE) {
        __shared__ int lcount[1024];
        __shared__ int lbase[1024];
        int t = threadIdx.x;
        for (int k = t; k < 1024; k += 256) lcount[k] = 0;
        __syncthreads();
        int base = bx * EPB + t;
#pragma unroll
        for (int k = 0; k < EPB / 256; k++) {
            int i = base + k * 256;
            if (i < N_EDGES) atomicAdd(&lcount[((unsigned)dst[i]) >> 6], 1);
        }
        __syncthreads();
        for (int k = t; k < NBUCK; k += 256) {
            int c = lcount[k];
            lbase[k] = c ? atomicAdd(&cursor[k], c) : 0;
            lcount[k] = 0;
        }
        __syncthreads();
#pragma unroll
        for (int k = 0; k < EPB / 256; k++) {
            int i = base + k * 256;
            if (i < N_EDGES) {
                int d = dst[i];
                int wb = ((unsigned)d) >> 6;
                int p = lbase[wb] + atomicAdd(&lcount[wb], 1);
                packed[p] = ((d & 63) << 16) | src[i];
            }
        }
    } else {
        gemm_body<128, true, false>(bx - NSTRIPE, X, whi, wlo, fcb, hi_out, lo_out, nullptr,
                                    N_NODES);
    }
}

// ---------------- per-node 1/deg (once; reused all 4 layers) ----------------

__global__ void __launch_bounds__(256) inv_kernel(const int* __restrict__ packed,
                                                  const int* __restrict__ boff,
                                                  float* __restrict__ inv) {
    __shared__ int dh[BKN];
    int b = blockIdx.x, t = threadIdx.x;
    if (t < BKN) dh[t] = 0;
    __syncthreads();
    int e0 = boff[b], e1 = boff[b + 1];
    for (int i = e0 + t; i < e1; i += 256) atomicAdd(&dh[((unsigned)packed[i]) >> 16], 1);
    __syncthreads();
    if (t < BKN) {
        int node = b * BKN + t;
        if (node < N_NODES) inv[node] = dh[t] ? 1.0f / (float)dh[t] : 0.0f;
    }
}

// ---------------- fused GIN layer: LDS agg + self-term + MFMA GEMM ----------------
// One block per 64-node bucket. Gather: wave per edge, coalesced 256B bf16 row,
// HW ds_add_f32 via unsafeAtomicAdd (r6 lesson: plain atomicAdd(float*) = CAS loop
// = 703us). 8-deep load pipelining. u never touches global.

template <int COLS, bool RELU, bool LAST>
__global__ void __launch_bounds__(256, 4) fused_layer(
    const unsigned short* __restrict__ hi_prev, const unsigned short* __restrict__ lo_prev,
    const int* __restrict__ packed, const int* __restrict__ boff, const float* __restrict__ inv,
    const float* __restrict__ eps, int layer, const unsigned short* __restrict__ Whi,
    const unsigned short* __restrict__ Wlo, const float* __restrict__ bias,
    unsigned short* __restrict__ hi_out, unsigned short* __restrict__ lo_out,
    float* __restrict__ out_last) {
    __shared__ float acc[BKN * ASTR];  // 33792 B -> 4 blocks/CU
    int b = blockIdx.x;
    int t = threadIdx.x;
    int wv = t >> 6, lane = t & 63;
    int node0 = b * BKN;

    for (int i = t; i < BKN * ASTR; i += 256) acc[i] = 0.f;
    __syncthreads();

    // ---- gather: mean-sum neighbors into LDS (hw ds_add_f32, fire-and-forget) ----
    int e0 = boff[b], e1 = boff[b + 1];
    int cnt = e1 - e0;
    int chunk = (cnt + 3) >> 2;
    int s = e0 + wv * chunk;
    int epnd = s + chunk;
    if (epnd > e1) epnd = e1;
    int i = s;
    for (; i + 7 < epnd; i += 8) {
        int w[8];
        unsigned v[8];
#pragma unroll
        for (int j = 0; j < 8; j++) w[j] = packed[i + j];
#pragma unroll
        for (int j = 0; j < 8; j++)
            v[j] = *((const unsigned*)(hi_prev + ((size_t)(w[j] & 0xFFFF)) * 128) + lane);
#pragma unroll
        for (int j = 0; j < 8; j++) {
            float* a = acc + (w[j] >> 16) * ASTR + lane * 2;
            unsafeAtomicAdd(a, bf2f((unsigned short)v[j]));
            unsafeAtomicAdd(a + 1, bf2f((unsigned short)(v[j] >> 16)));
        }
    }
    for (; i < epnd; i++) {
        int w = packed[i];
        unsigned v = *((const unsigned*)(hi_prev + ((size_t)(w & 0xFFFF)) * 128) + lane);
        float* a = acc + (w >> 16) * ASTR + lane * 2;
        unsafeAtomicAdd(a, bf2f((unsigned short)v));
        unsafeAtomicAdd(a + 1, bf2f((unsigned short)(v >> 16)));
    }
    __syncthreads();

    // ---- self-term + normalize: u = (1+eps)*(hi+lo) + acc*inv ----
    float ep = 1.0f + eps[layer];
    for (int g = t; g < BKN * 32; g += 256) {
        int row = g >> 5;
        int col = (g & 31) << 2;
        int node = node0 + row;
        if (node < N_NODES) {
            float iv = inv[node];
            const unsigned short* hp = hi_prev + (size_t)node * 128 + col;
            const unsigned short* lp = lo_prev + (size_t)node * 128 + col;
            float* ap = acc + row * ASTR + col;
#pragma unroll
            for (int k = 0; k < 4; k++) {
                float self = bf2f(hp[k]) + bf2f(lp[k]);
                ap[k] = ep * self + ap[k] * iv;
            }
        }
    }
    __syncthreads();

    // ---- GEMM from LDS A (split bf16, 3-product) ----
    int m = lane & 15, quad = lane >> 4;
    int lr0 = wv * 16;
    short8 ahi[4], alo[4];
    const float* ar = acc + (lr0 + m) * ASTR + quad * 8;
#pragma unroll
    for (int kc = 0; kc < 4; kc++) {
        float4 f0 = *(const float4*)(ar + kc * 32);
        float4 f1 = *(const float4*)(ar + kc * 32 + 4);
        float fv[8] = {f0.x, f0.y, f0.z, f0.w, f1.x, f1.y, f1.z, f1.w};
#pragma unroll
        for (int j = 0; j < 8; j++) {
            unsigned short hh = f2bf(fv[j]);
            ahi[kc][j] = (short)hh;
            alo[kc][j] = (short)f2bf(fv[j] - bf2f(hh));
        }
    }
#pragma unroll
    for (int nt = 0; nt < COLS / 16; nt++) {
        int n = nt * 16 + m;
        const unsigned short* bhp = Whi + (size_t)n * 128 + quad * 8;
        const unsigned short* blp = Wlo + (size_t)n * 128 + quad * 8;
        float4v c = {0.f, 0.f, 0.f, 0.f};
#pragma unroll
        for (int kc = 0; kc < 4; kc++) {
            short8 bh = *(const short8*)(bhp + kc * 32);
            short8 bl = *(const short8*)(blp + kc * 32);
            c = __builtin_amdgcn_mfma_f32_16x16x32_bf16(ahi[kc], bh, c, 0, 0, 0);
            c = __builtin_amdgcn_mfma_f32_16x16x32_bf16(alo[kc], bh, c, 0, 0, 0);
            c = __builtin_amdgcn_mfma_f32_16x16x32_bf16(ahi[kc], bl, c, 0, 0, 0);
        }
        float bv = bias[n];
#pragma unroll
        for (int k = 0; k < 4; k++) {
            int node = node0 + lr0 + quad * 4 + k;
            if (node < N_NODES) {
                float v = c[k] + bv;
                if (RELU) v = fmaxf(v, 0.f);
                if (LAST) {
                    out_last[(size_t)node * COLS + n] = v;
                } else {
                    unsigned short hh = f2bf(v);
                    hi_out[(size_t)node * COLS + n] = hh;
                    lo_out[(size_t)node * COLS + n] = f2bf(v - bf2f(hh));
                }
            }
        }
    }
}

// ---------------- launch ----------------

extern "C" void kernel_launch(void* const* d_in, const int* in_sizes, int n_in,
                              void* d_out, int out_size, void* d_ws, size_t ws_size,
                              hipStream_t stream) {
    const float* X   = (const float*)d_in[0];
    const float* fcW = (const float*)d_in[1];
    const float* fcb = (const float*)d_in[2];
    const float* W   = (const float*)d_in[3];
    const float* b   = (const float*)d_in[4];
    const float* Wl  = (const float*)d_in[5];
    const float* bl  = (const float*)d_in[6];
    const float* eps = (const float*)d_in[7];
    const int* src   = (const int*)d_in[8];
    const int* dst   = (const int*)d_in[9];
    float* out = (float*)d_out;

    // workspace carve (~55 MB)
    const size_t NF = (size_t)N_NODES * 128;
    unsigned short* hi_a = (unsigned short*)d_ws;         // NF bf16
    unsigned short* lo_a = hi_a + NF;
    unsigned short* hi_b = lo_a + NF;
    unsigned short* lo_b = hi_b + NF;
    unsigned short* whi  = lo_b + NF;                     // 73728
    unsigned short* wlo  = whi + 73728;                   // 73728
    float* inv   = (float*)(wlo + 73728);                 // N_NODES
    int* bcnt    = (int*)(inv + N_NODES);                 // 1024
    int* boff    = bcnt + 1024;                           // NBUCK+1
    int* cursor  = boff + NBUCK + 1;                      // NBUCK
    int* packed  = cursor + NBUCK;                        // N_EDGES

    const int gemm_blocks = (N_NODES + 63) / 64;        // 782
    const int prep_blocks = (73728 + 255) / 256;        // 288

    hipMemsetAsync(bcnt, 0, 1024 * sizeof(int), stream);
    fused_hist_prep<<<NSTRIPE + prep_blocks, 256, 0, stream>>>(dst, bcnt, fcW, W, Wl, whi, wlo);
    bucket_scan<<<1, 1024, 0, stream>>>(bcnt, boff, cursor);
    fused_binA_gemm<<<NSTRIPE + gemm_blocks, 256, 0, stream>>>(src, dst, cursor, packed, X, whi,
                                                               wlo, fcb, hi_a, lo_a);
    inv_kernel<<<NBUCK, 256, 0, stream>>>(packed, boff, inv);

    // 3 hidden GIN layers (a->b->a->b), then last layer -> d_out
    fused_layer<128, true, false><<<NBUCK, 256, 0, stream>>>(
        hi_a, lo_a, packed, boff, inv, eps, 0, whi + 16384, wlo + 16384, b, hi_b, lo_b, nullptr);
    fused_layer<128, true, false><<<NBUCK, 256, 0, stream>>>(
        hi_b, lo_b, packed, boff, inv, eps, 1, whi + 32768, wlo + 32768, b + 128, hi_a, lo_a,
        nullptr);
    fused_layer<128, true, false><<<NBUCK, 256, 0, stream>>>(
        hi_a, lo_a, packed, boff, inv, eps, 2, whi + 49152, wlo + 49152, b + 256, hi_b, lo_b,
        nullptr);
    fused_layer<64, false, true><<<NBUCK, 256, 0, stream>>>(
        hi_b, lo_b, packed, boff, inv, eps, 3, whi + 65536, wlo + 65536, bl, nullptr, nullptr,
        out);
}

// Round 8
// 553.236 us; speedup vs baseline: 5.3134x; 5.3134x over previous
//
#include <hip/hip_runtime.h>

#define N_NODES 50000
#define N_EDGES 800000
#define BKN 64                      // nodes per bucket: bucket = dst >> 6
#define NBUCK 782                   // ceil(50000/64)
#define ASTR 132                    // LDS u-matrix row stride (floats)
#define EPB 2048                    // edges per stripe-block (straggler-tail control)
#define NSTRIPE ((N_EDGES + EPB - 1) / EPB)  // 391

typedef __attribute__((ext_vector_type(8))) short short8;
typedef __attribute__((ext_vector_type(4))) float float4v;

__device__ inline unsigned short f2bf(float f) {
    unsigned u = __float_as_uint(f);
    unsigned r = u + 0x7fff + ((u >> 16) & 1);
    return (unsigned short)(r >> 16);
}
__device__ inline float bf2f(unsigned short h) {
    return __uint_as_float(((unsigned)h) << 16);
}

// ---------------- fused: bucket histogram (391 blocks) + weight split (288) ----------

__global__ void __launch_bounds__(256) fused_hist_prep(
    const int* __restrict__ dst, int* __restrict__ bcnt, const float* __restrict__ fcW,
    const float* __restrict__ W, const float* __restrict__ Wl, unsigned short* __restrict__ hi,
    unsigned short* __restrict__ lo) {
    int bx = blockIdx.x;
    if (bx < NSTRIPE) {
        __shared__ int lhist[1024];
        int t = threadIdx.x;
        for (int k = t; k < 1024; k += 256) lhist[k] = 0;
        __syncthreads();
        int base = bx * EPB + t;
#pragma unroll
        for (int k = 0; k < EPB / 256; k++) {
            int i = base + k * 256;
            if (i < N_EDGES) atomicAdd(&lhist[((unsigned)dst[i]) >> 6], 1);
        }
        __syncthreads();
        for (int k = t; k < NBUCK; k += 256)
            if (lhist[k]) atomicAdd(&bcnt[k], lhist[k]);
    } else {
        // weight split: [0,16384) fcW | [16384,65536) W | [65536,73728) W_last
        int i = (bx - NSTRIPE) * 256 + threadIdx.x;
        float v;
        if (i < 16384) v = fcW[i];
        else if (i < 65536) v = W[i - 16384];
        else if (i < 73728) v = Wl[i - 65536];
        else return;
        unsigned short h = f2bf(v);
        hi[i] = h;
        lo[i] = f2bf(v - bf2f(h));
    }
}

// ---------------- bucket offsets (1 block, 1024 threads) ----------------

__global__ void bucket_scan(const int* __restrict__ bcnt, int* __restrict__ boff,
                            int* __restrict__ cursor, int* __restrict__ row_ptr) {
    __shared__ int sm[1024];
    int t = threadIdx.x;
    int v = (t < NBUCK) ? bcnt[t] : 0;
    sm[t] = v;
    __syncthreads();
    for (int o = 1; o < 1024; o <<= 1) {
        int x = sm[t];
        int a = (t >= o) ? sm[t - o] : 0;
        __syncthreads();
        sm[t] = x + a;
        __syncthreads();
    }
    if (t < NBUCK) {
        boff[t] = sm[t] - v;
        cursor[t] = sm[t] - v;
    }
    if (t == NBUCK - 1) {
        boff[NBUCK] = sm[t];
        row_ptr[N_NODES] = sm[t];
    }
}

// ---------------- split-bf16 MFMA GEMM body (global A) ----------------
// D = Ahi*Whi + Alo*Whi + Ahi*Wlo (missing Alo*Wlo ~ 2^-18 rel).

template <int COLS, bool RELU, bool LAST>
__device__ __forceinline__ void gemm_body(int bx, const float* __restrict__ U,
                                          const unsigned short* __restrict__ Whi,
                                          const unsigned short* __restrict__ Wlo,
                                          const float* __restrict__ bias,
                                          unsigned short* __restrict__ hi_out,
                                          unsigned short* __restrict__ lo_out,
                                          float* __restrict__ out_last, int nrows) {
    int wave = threadIdx.x >> 6;
    int lane = threadIdx.x & 63;
    int m = lane & 15;
    int quad = lane >> 4;
    int r0 = bx * 64 + wave * 16;
    int rowA = r0 + m;
    if (rowA >= nrows) rowA = nrows - 1;  // clamp OOB loads (stores guarded)

    short8 ahi[4], alo[4];
    const float* arow = U + (size_t)rowA * 128 + quad * 8;
#pragma unroll
    for (int kc = 0; kc < 4; kc++) {
        float4 f0 = *(const float4*)(arow + kc * 32);
        float4 f1 = *(const float4*)(arow + kc * 32 + 4);
        float fv[8] = {f0.x, f0.y, f0.z, f0.w, f1.x, f1.y, f1.z, f1.w};
#pragma unroll
        for (int j = 0; j < 8; j++) {
            unsigned short h = f2bf(fv[j]);
            ahi[kc][j] = (short)h;
            alo[kc][j] = (short)f2bf(fv[j] - bf2f(h));
        }
    }

#pragma unroll
    for (int nt = 0; nt < COLS / 16; nt++) {
        int n = nt * 16 + m;
        const unsigned short* bhp = Whi + (size_t)n * 128 + quad * 8;
        const unsigned short* blp = Wlo + (size_t)n * 128 + quad * 8;
        float4v c = {0.f, 0.f, 0.f, 0.f};
#pragma unroll
        for (int kc = 0; kc < 4; kc++) {
            short8 bh = *(const short8*)(bhp + kc * 32);
            short8 bl = *(const short8*)(blp + kc * 32);
            c = __builtin_amdgcn_mfma_f32_16x16x32_bf16(ahi[kc], bh, c, 0, 0, 0);
            c = __builtin_amdgcn_mfma_f32_16x16x32_bf16(alo[kc], bh, c, 0, 0, 0);
            c = __builtin_amdgcn_mfma_f32_16x16x32_bf16(ahi[kc], bl, c, 0, 0, 0);
        }
        float bv = bias[n];
#pragma unroll
        for (int k = 0; k < 4; k++) {
            int r = r0 + quad * 4 + k;
            if (r < nrows) {
                float v = c[k] + bv;
                if (RELU) v = fmaxf(v, 0.f);
                if (LAST) {
                    out_last[(size_t)r * COLS + n] = v;
                } else {
                    unsigned short hh = f2bf(v);
                    hi_out[(size_t)r * COLS + n] = hh;
                    lo_out[(size_t)r * COLS + n] = f2bf(v - bf2f(hh));
                }
            }
        }
    }
}

// ---------------- fused: pass A binning (391 blocks) + SLP GEMM (782) ----------

__global__ void __launch_bounds__(256) fused_binA_gemm(
    const int* __restrict__ src, const int* __restrict__ dst, int* __restrict__ cursor,
    int* __restrict__ packed, const float* __restrict__ X, const unsigned short* __restrict__ whi,
    const unsigned short* __restrict__ wlo, const float* __restrict__ fcb,
    unsigned short* __restrict__ hi_out, unsigned short* __restrict__ lo_out) {
    int bx = blockIdx.x;
    if (bx < NSTRIPE) {
        __shared__ int lcount[1024];
        __shared__ int lbase[1024];
        int t = threadIdx.x;
        for (int k = t; k < 1024; k += 256) lcount[k] = 0;
        __syncthreads();
        int base = bx * EPB + t;
#pragma unroll
        for (int k = 0; k < EPB / 256; k++) {
            int i = base + k * 256;
            if (i < N_EDGES) atomicAdd(&lcount[((unsigned)dst[i]) >> 6], 1);
        }
        __syncthreads();
        for (int k = t; k < NBUCK; k += 256) {
            int c = lcount[k];
            lbase[k] = c ? atomicAdd(&cursor[k], c) : 0;
            lcount[k] = 0;
        }
        __syncthreads();
#pragma unroll
        for (int k = 0; k < EPB / 256; k++) {
            int i = base + k * 256;
            if (i < N_EDGES) {
                int d = dst[i];
                int wb = ((unsigned)d) >> 6;
                int p = lbase[wb] + atomicAdd(&lcount[wb], 1);
                packed[p] = ((d & 63) << 16) | src[i];
            }
        }
    } else {
        gemm_body<128, true, false>(bx - NSTRIPE, X, whi, wlo, fcb, hi_out, lo_out, nullptr,
                                    N_NODES);
    }
}

// ---------------- pass B: per-64-node-bucket counting sort -> row_ptr + esrc ----------

__global__ void __launch_bounds__(256) binB_kernel(const int* __restrict__ packed,
                                                   const int* __restrict__ boff,
                                                   int* __restrict__ row_ptr,
                                                   int* __restrict__ esrc) {
    __shared__ int hist[BKN];
    __shared__ int sm[BKN];
    __shared__ int curs[BKN];
    int b = blockIdx.x, t = threadIdx.x;
    if (t < BKN) hist[t] = 0;
    __syncthreads();
    int e0 = boff[b], e1 = boff[b + 1];
    for (int i = e0 + t; i < e1; i += 256) atomicAdd(&hist[((unsigned)packed[i]) >> 16], 1);
    __syncthreads();
    int v = (t < BKN) ? hist[t] : 0;
    if (t < BKN) sm[t] = v;
    __syncthreads();
    for (int o = 1; o < BKN; o <<= 1) {
        int x = (t < BKN) ? sm[t] : 0;
        int a = (t >= o && t < BKN) ? sm[t - o] : 0;
        __syncthreads();
        if (t < BKN) sm[t] = x + a;
        __syncthreads();
    }
    if (t < BKN) {
        int excl = sm[t] - v;
        curs[t] = excl;
        int node = b * BKN + t;
        if (node < N_NODES) row_ptr[node] = e0 + excl;
    }
    __syncthreads();
    for (int i = e0 + t; i < e1; i += 256) {
        unsigned w = (unsigned)packed[i];
        int p = atomicAdd(&curs[w >> 16], 1);
        esrc[e0 + p] = (int)(w & 0xFFFFu);
    }
}

// ---------------- fused GIN layer: CSR register-gather + LDS u + MFMA GEMM ----------
// One block (512 thr = 8 waves) per 64-node bucket. Wave wv owns nodes
// [node0+wv*8, +8): walks each node's sorted esrc range, gathering one dword/lane
// (256B bf16 row, coalesced), 8-deep pipelined, REGISTER accumulation (no atomics
// — r6/r7 lesson: per-edge LDS atomic scatter = 704us regardless of atomic kind).
// u -> LDS, then 8-wave MFMA epilogue (4 row-tiles x 2 col-halves).

template <int COLS, bool RELU, bool LAST>
__global__ void __launch_bounds__(512, 4) fused_layer(
    const unsigned short* __restrict__ hi_prev, const unsigned short* __restrict__ lo_prev,
    const int* __restrict__ row_ptr, const int* __restrict__ esrc, const float* __restrict__ eps,
    int layer, const unsigned short* __restrict__ Whi, const unsigned short* __restrict__ Wlo,
    const float* __restrict__ bias, unsigned short* __restrict__ hi_out,
    unsigned short* __restrict__ lo_out, float* __restrict__ out_last) {
    __shared__ float acc[BKN * ASTR];  // 33792 B -> 2+ blocks/CU at 512 thr
    int b = blockIdx.x;
    int t = threadIdx.x;
    int wv = t >> 6, lane = t & 63;
    int node0 = b * BKN;
    float ep = 1.0f + eps[layer];

    // ---- gather phase: 8 nodes per wave, register accumulate ----
#pragma unroll 1
    for (int k = 0; k < 8; k++) {
        int lrow = wv * 8 + k;
        int node = node0 + lrow;
        float ux = 0.f, uy = 0.f;
        if (node < N_NODES) {
            int beg = row_ptr[node];
            int end = row_ptr[node + 1];
            float sx = 0.f, sy = 0.f;
            int e = beg;
            for (; e + 7 < end; e += 8) {
                unsigned v[8];
#pragma unroll
                for (int j = 0; j < 8; j++)
                    v[j] = *((const unsigned*)(hi_prev + (size_t)esrc[e + j] * 128) + lane);
#pragma unroll
                for (int j = 0; j < 8; j++) {
                    sx += bf2f((unsigned short)v[j]);
                    sy += bf2f((unsigned short)(v[j] >> 16));
                }
            }
            for (; e < end; e++) {
                unsigned v = *((const unsigned*)(hi_prev + (size_t)esrc[e] * 128) + lane);
                sx += bf2f((unsigned short)v);
                sy += bf2f((unsigned short)(v >> 16));
            }
            float iv = (end > beg) ? 1.0f / (float)(end - beg) : 0.f;
            unsigned hv = *((const unsigned*)(hi_prev + (size_t)node * 128) + lane);
            unsigned lv = *((const unsigned*)(lo_prev + (size_t)node * 128) + lane);
            ux = ep * (bf2f((unsigned short)hv) + bf2f((unsigned short)lv)) + sx * iv;
            uy = ep * (bf2f((unsigned short)(hv >> 16)) + bf2f((unsigned short)(lv >> 16))) +
                 sy * iv;
        }
        float* ap = acc + lrow * ASTR + lane * 2;
        ap[0] = ux;
        ap[1] = uy;
    }
    __syncthreads();

    // ---- MFMA epilogue: wave -> row-tile (wv&3)*16, col-half (wv>>2) ----
    int m = lane & 15, quad = lane >> 4;
    int lr0 = (wv & 3) * 16;
    int nhalf = wv >> 2;
    constexpr int NT = COLS / 32;  // tiles per col-half
    short8 ahi[4], alo[4];
    const float* ar = acc + (lr0 + m) * ASTR + quad * 8;
#pragma unroll
    for (int kc = 0; kc < 4; kc++) {
        float4 f0 = *(const float4*)(ar + kc * 32);
        float4 f1 = *(const float4*)(ar + kc * 32 + 4);
        float fv[8] = {f0.x, f0.y, f0.z, f0.w, f1.x, f1.y, f1.z, f1.w};
#pragma unroll
        for (int j = 0; j < 8; j++) {
            unsigned short hh = f2bf(fv[j]);
            ahi[kc][j] = (short)hh;
            alo[kc][j] = (short)f2bf(fv[j] - bf2f(hh));
        }
    }
#pragma unroll
    for (int nt = 0; nt < NT; nt++) {
        int n = (nhalf * NT + nt) * 16 + m;
        const unsigned short* bhp = Whi + (size_t)n * 128 + quad * 8;
        const unsigned short* blp = Wlo + (size_t)n * 128 + quad * 8;
        float4v c = {0.f, 0.f, 0.f, 0.f};
#pragma unroll
        for (int kc = 0; kc < 4; kc++) {
            short8 bh = *(const short8*)(bhp + kc * 32);
            short8 bl = *(const short8*)(blp + kc * 32);
            c = __builtin_amdgcn_mfma_f32_16x16x32_bf16(ahi[kc], bh, c, 0, 0, 0);
            c = __builtin_amdgcn_mfma_f32_16x16x32_bf16(alo[kc], bh, c, 0, 0, 0);
            c = __builtin_amdgcn_mfma_f32_16x16x32_bf16(ahi[kc], bl, c, 0, 0, 0);
        }
        float bv = bias[n];
#pragma unroll
        for (int k = 0; k < 4; k++) {
            int node = node0 + lr0 + quad * 4 + k;
            if (node < N_NODES) {
                float v = c[k] + bv;
                if (RELU) v = fmaxf(v, 0.f);
                if (LAST) {
                    out_last[(size_t)node * COLS + n] = v;
                } else {
                    unsigned short hh = f2bf(v);
                    hi_out[(size_t)node * COLS + n] = hh;
                    lo_out[(size_t)node * COLS + n] = f2bf(v - bf2f(hh));
                }
            }
        }
    }
}

// ---------------- launch ----------------

extern "C" void kernel_launch(void* const* d_in, const int* in_sizes, int n_in,
                              void* d_out, int out_size, void* d_ws, size_t ws_size,
                              hipStream_t stream) {
    const float* X   = (const float*)d_in[0];
    const float* fcW = (const float*)d_in[1];
    const float* fcb = (const float*)d_in[2];
    const float* W   = (const float*)d_in[3];
    const float* b   = (const float*)d_in[4];
    const float* Wl  = (const float*)d_in[5];
    const float* bl  = (const float*)d_in[6];
    const float* eps = (const float*)d_in[7];
    const int* src   = (const int*)d_in[8];
    const int* dst   = (const int*)d_in[9];
    float* out = (float*)d_out;

    // workspace carve (~58 MB)
    const size_t NF = (size_t)N_NODES * 128;
    unsigned short* hi_a = (unsigned short*)d_ws;         // NF bf16
    unsigned short* lo_a = hi_a + NF;
    unsigned short* hi_b = lo_a + NF;
    unsigned short* lo_b = hi_b + NF;
    unsigned short* whi  = lo_b + NF;                     // 73728
    unsigned short* wlo  = whi + 73728;                   // 73728
    int* bcnt    = (int*)(wlo + 73728);                   // 1024
    int* boff    = bcnt + 1024;                           // NBUCK+1
    int* cursor  = boff + NBUCK + 1;                      // NBUCK
    int* row_ptr = cursor + NBUCK;                        // N_NODES+1
    int* packed  = row_ptr + N_NODES + 1;                 // N_EDGES
    int* esrc    = packed + N_EDGES;                      // N_EDGES

    const int gemm_blocks = (N_NODES + 63) / 64;        // 782
    const int prep_blocks = (73728 + 255) / 256;        // 288

    hipMemsetAsync(bcnt, 0, 1024 * sizeof(int), stream);
    fused_hist_prep<<<NSTRIPE + prep_blocks, 256, 0, stream>>>(dst, bcnt, fcW, W, Wl, whi, wlo);
    bucket_scan<<<1, 1024, 0, stream>>>(bcnt, boff, cursor, row_ptr);
    fused_binA_gemm<<<NSTRIPE + gemm_blocks, 256, 0, stream>>>(src, dst, cursor, packed, X, whi,
                                                               wlo, fcb, hi_a, lo_a);
    binB_kernel<<<NBUCK, 256, 0, stream>>>(packed, boff, row_ptr, esrc);

    // 3 hidden GIN layers (a->b->a->b), then last layer -> d_out
    fused_layer<128, true, false><<<NBUCK, 512, 0, stream>>>(
        hi_a, lo_a, row_ptr, esrc, eps, 0, whi + 16384, wlo + 16384, b, hi_b, lo_b, nullptr);
    fused_layer<128, true, false><<<NBUCK, 512, 0, stream>>>(
        hi_b, lo_b, row_ptr, esrc, eps, 1, whi + 32768, wlo + 32768, b + 128, hi_a, lo_a,
        nullptr);
    fused_layer<128, true, false><<<NBUCK, 512, 0, stream>>>(
        hi_a, lo_a, row_ptr, esrc, eps, 2, whi + 49152, wlo + 49152, b + 256, hi_b, lo_b,
        nullptr);
    fused_layer<64, false, true><<<NBUCK, 512, 0, stream>>>(
        hi_b, lo_b, row_ptr, esrc, eps, 3, whi + 65536, wlo + 65536, bl, nullptr, nullptr, out);
}

// Round 9
// 429.838 us; speedup vs baseline: 6.8388x; 1.2871x over previous
//
#include <hip/hip_runtime.h>

#define N_NODES 50000
#define N_EDGES 800000
#define BKN 64                      // nodes per bucket: bucket = dst >> 6
#define NBUCK 782                   // ceil(50000/64)
#define EPB 2048                    // edges per stripe-block (straggler-tail control)
#define NSTRIPE ((N_EDGES + EPB - 1) / EPB)  // 391

typedef __attribute__((ext_vector_type(8))) short short8;
typedef __attribute__((ext_vector_type(4))) float float4v;

__device__ inline unsigned short f2bf(float f) {
    unsigned u = __float_as_uint(f);
    unsigned r = u + 0x7fff + ((u >> 16) & 1);
    return (unsigned short)(r >> 16);
}
__device__ inline float bf2f(unsigned short h) {
    return __uint_as_float(((unsigned)h) << 16);
}
__device__ inline void acc8(float* s, uint4 v) {
    s[0] += bf2f((unsigned short)v.x); s[1] += bf2f((unsigned short)(v.x >> 16));
    s[2] += bf2f((unsigned short)v.y); s[3] += bf2f((unsigned short)(v.y >> 16));
    s[4] += bf2f((unsigned short)v.z); s[5] += bf2f((unsigned short)(v.z >> 16));
    s[6] += bf2f((unsigned short)v.w); s[7] += bf2f((unsigned short)(v.w >> 16));
}

// ---------------- fused: bucket histogram (391 blocks) + weight split (288) ----------

__global__ void __launch_bounds__(256) fused_hist_prep(
    const int* __restrict__ dst, int* __restrict__ bcnt, const float* __restrict__ fcW,
    const float* __restrict__ W, const float* __restrict__ Wl, unsigned short* __restrict__ hi,
    unsigned short* __restrict__ lo) {
    int bx = blockIdx.x;
    if (bx < NSTRIPE) {
        __shared__ int lhist[1024];
        int t = threadIdx.x;
        for (int k = t; k < 1024; k += 256) lhist[k] = 0;
        __syncthreads();
        int base = bx * EPB + t;
#pragma unroll
        for (int k = 0; k < EPB / 256; k++) {
            int i = base + k * 256;
            if (i < N_EDGES) atomicAdd(&lhist[((unsigned)dst[i]) >> 6], 1);
        }
        __syncthreads();
        for (int k = t; k < NBUCK; k += 256)
            if (lhist[k]) atomicAdd(&bcnt[k], lhist[k]);
    } else {
        // weight split: [0,16384) fcW | [16384,65536) W | [65536,73728) W_last
        int i = (bx - NSTRIPE) * 256 + threadIdx.x;
        float v;
        if (i < 16384) v = fcW[i];
        else if (i < 65536) v = W[i - 16384];
        else if (i < 73728) v = Wl[i - 65536];
        else return;
        unsigned short h = f2bf(v);
        hi[i] = h;
        lo[i] = f2bf(v - bf2f(h));
    }
}

// ---------------- bucket offsets (1 block, 1024 threads) ----------------

__global__ void bucket_scan(const int* __restrict__ bcnt, int* __restrict__ boff,
                            int* __restrict__ cursor, int* __restrict__ row_ptr) {
    __shared__ int sm[1024];
    int t = threadIdx.x;
    int v = (t < NBUCK) ? bcnt[t] : 0;
    sm[t] = v;
    __syncthreads();
    for (int o = 1; o < 1024; o <<= 1) {
        int x = sm[t];
        int a = (t >= o) ? sm[t - o] : 0;
        __syncthreads();
        sm[t] = x + a;
        __syncthreads();
    }
    if (t < NBUCK) {
        boff[t] = sm[t] - v;
        cursor[t] = sm[t] - v;
    }
    if (t == NBUCK - 1) {
        boff[NBUCK] = sm[t];
        row_ptr[N_NODES] = sm[t];
    }
}

// ---------------- split-bf16 MFMA GEMM body (global fp32 A) ----------------
// D = Ahi*Whi + Alo*Whi + Ahi*Wlo (missing Alo*Wlo ~ 2^-18 rel).

template <int COLS, bool RELU, bool LAST>
__device__ __forceinline__ void gemm_body(int bx, const float* __restrict__ U,
                                          const unsigned short* __restrict__ Whi,
                                          const unsigned short* __restrict__ Wlo,
                                          const float* __restrict__ bias,
                                          unsigned short* __restrict__ hi_out,
                                          unsigned short* __restrict__ lo_out,
                                          float* __restrict__ out_last, int nrows) {
    int wave = threadIdx.x >> 6;
    int lane = threadIdx.x & 63;
    int m = lane & 15;
    int quad = lane >> 4;
    int r0 = bx * 64 + wave * 16;
    int rowA = r0 + m;
    if (rowA >= nrows) rowA = nrows - 1;  // clamp OOB loads (stores guarded)

    short8 ahi[4], alo[4];
    const float* arow = U + (size_t)rowA * 128 + quad * 8;
#pragma unroll
    for (int kc = 0; kc < 4; kc++) {
        float4 f0 = *(const float4*)(arow + kc * 32);
        float4 f1 = *(const float4*)(arow + kc * 32 + 4);
        float fv[8] = {f0.x, f0.y, f0.z, f0.w, f1.x, f1.y, f1.z, f1.w};
#pragma unroll
        for (int j = 0; j < 8; j++) {
            unsigned short h = f2bf(fv[j]);
            ahi[kc][j] = (short)h;
            alo[kc][j] = (short)f2bf(fv[j] - bf2f(h));
        }
    }

#pragma unroll
    for (int nt = 0; nt < COLS / 16; nt++) {
        int n = nt * 16 + m;
        const unsigned short* bhp = Whi + (size_t)n * 128 + quad * 8;
        const unsigned short* blp = Wlo + (size_t)n * 128 + quad * 8;
        float4v c = {0.f, 0.f, 0.f, 0.f};
#pragma unroll
        for (int kc = 0; kc < 4; kc++) {
            short8 bh = *(const short8*)(bhp + kc * 32);
            short8 bl = *(const short8*)(blp + kc * 32);
            c = __builtin_amdgcn_mfma_f32_16x16x32_bf16(ahi[kc], bh, c, 0, 0, 0);
            c = __builtin_amdgcn_mfma_f32_16x16x32_bf16(alo[kc], bh, c, 0, 0, 0);
            c = __builtin_amdgcn_mfma_f32_16x16x32_bf16(ahi[kc], bl, c, 0, 0, 0);
        }
        float bv = bias[n];
#pragma unroll
        for (int k = 0; k < 4; k++) {
            int r = r0 + quad * 4 + k;
            if (r < nrows) {
                float v = c[k] + bv;
                if (RELU) v = fmaxf(v, 0.f);
                if (LAST) {
                    out_last[(size_t)r * COLS + n] = v;
                } else {
                    unsigned short hh = f2bf(v);
                    hi_out[(size_t)r * COLS + n] = hh;
                    lo_out[(size_t)r * COLS + n] = f2bf(v - bf2f(hh));
                }
            }
        }
    }
}

template <int COLS, bool RELU, bool LAST>
__global__ void __launch_bounds__(256) gemm_mfma(const float* __restrict__ U,
                                                 const unsigned short* __restrict__ Whi,
                                                 const unsigned short* __restrict__ Wlo,
                                                 const float* __restrict__ bias,
                                                 unsigned short* __restrict__ hi_out,
                                                 unsigned short* __restrict__ lo_out,
                                                 float* __restrict__ out_last, int nrows) {
    gemm_body<COLS, RELU, LAST>(blockIdx.x, U, Whi, Wlo, bias, hi_out, lo_out, out_last, nrows);
}

// ---------------- fused: pass A binning (391 blocks) + SLP GEMM (782) ----------

__global__ void __launch_bounds__(256) fused_binA_gemm(
    const int* __restrict__ src, const int* __restrict__ dst, int* __restrict__ cursor,
    int* __restrict__ packed, const float* __restrict__ X, const unsigned short* __restrict__ whi,
    const unsigned short* __restrict__ wlo, const float* __restrict__ fcb,
    unsigned short* __restrict__ hi_out, unsigned short* __restrict__ lo_out) {
    int bx = blockIdx.x;
    if (bx < NSTRIPE) {
        __shared__ int lcount[1024];
        __shared__ int lbase[1024];
        int t = threadIdx.x;
        for (int k = t; k < 1024; k += 256) lcount[k] = 0;
        __syncthreads();
        int base = bx * EPB + t;
#pragma unroll
        for (int k = 0; k < EPB / 256; k++) {
            int i = base + k * 256;
            if (i < N_EDGES) atomicAdd(&lcount[((unsigned)dst[i]) >> 6], 1);
        }
        __syncthreads();
        for (int k = t; k < NBUCK; k += 256) {
            int c = lcount[k];
            lbase[k] = c ? atomicAdd(&cursor[k], c) : 0;
            lcount[k] = 0;
        }
        __syncthreads();
#pragma unroll
        for (int k = 0; k < EPB / 256; k++) {
            int i = base + k * 256;
            if (i < N_EDGES) {
                int d = dst[i];
                int wb = ((unsigned)d) >> 6;
                int p = lbase[wb] + atomicAdd(&lcount[wb], 1);
                packed[p] = ((d & 63) << 16) | src[i];
            }
        }
    } else {
        gemm_body<128, true, false>(bx - NSTRIPE, X, whi, wlo, fcb, hi_out, lo_out, nullptr,
                                    N_NODES);
    }
}

// ---------------- pass B: per-64-node-bucket counting sort -> row_ptr + esrc ----------

__global__ void __launch_bounds__(256) binB_kernel(const int* __restrict__ packed,
                                                   const int* __restrict__ boff,
                                                   int* __restrict__ row_ptr,
                                                   int* __restrict__ esrc) {
    __shared__ int hist[BKN];
    __shared__ int sm[BKN];
    __shared__ int curs[BKN];
    int b = blockIdx.x, t = threadIdx.x;
    if (t < BKN) hist[t] = 0;
    __syncthreads();
    int e0 = boff[b], e1 = boff[b + 1];
    for (int i = e0 + t; i < e1; i += 256) atomicAdd(&hist[((unsigned)packed[i]) >> 16], 1);
    __syncthreads();
    int v = (t < BKN) ? hist[t] : 0;
    if (t < BKN) sm[t] = v;
    __syncthreads();
    for (int o = 1; o < BKN; o <<= 1) {
        int x = (t < BKN) ? sm[t] : 0;
        int a = (t >= o && t < BKN) ? sm[t - o] : 0;
        __syncthreads();
        if (t < BKN) sm[t] = x + a;
        __syncthreads();
    }
    if (t < BKN) {
        int excl = sm[t] - v;
        curs[t] = excl;
        int node = b * BKN + t;
        if (node < N_NODES) row_ptr[node] = e0 + excl;
    }
    __syncthreads();
    for (int i = e0 + t; i < e1; i += 256) {
        unsigned w = (unsigned)packed[i];
        int p = atomicAdd(&curs[w >> 16], 1);
        esrc[e0 + p] = (int)(w & 0xFFFFu);
    }
}

// ---------------- Aggregation: u = (1+eps)*h + mean_in(h), 4 rows per instr ----------
// One wave per node. Wave splits into 4 groups x 16 lanes: group g loads row
// esrc[e+4i+g] as uint4 (16 lanes x 16B = full 256B bf16 row). 4 gathers in
// flight = 16 rows outstanding per wave (vs 4 with lane-wide rows) — attacks
// the measured latency/MLP bound. Per-lane 8 fp32 partials; shfl-fold groups;
// lanes 0-15 add self term and write fp32 u.

__global__ void __launch_bounds__(256) agg_kernel(const unsigned short* __restrict__ hi_prev,
                                                  const unsigned short* __restrict__ lo_prev,
                                                  const int* __restrict__ row_ptr,
                                                  const int* __restrict__ esrc,
                                                  const float* __restrict__ eps, int layer,
                                                  float* __restrict__ u) {
    int gtid = blockIdx.x * 256 + threadIdx.x;
    int node = gtid >> 6;
    if (node >= N_NODES) return;
    int lane = threadIdx.x & 63;
    int g = lane >> 4;   // row group 0..3
    int c = lane & 15;   // 16B chunk within row
    node = __builtin_amdgcn_readfirstlane(node);
    int beg = __builtin_amdgcn_readfirstlane(row_ptr[node]);
    int end = __builtin_amdgcn_readfirstlane(row_ptr[node + 1]);

    float s[8] = {0.f, 0.f, 0.f, 0.f, 0.f, 0.f, 0.f, 0.f};
    int e = beg;
#pragma unroll 1
    for (; e + 15 < end; e += 16) {
        int i0 = esrc[e + g];
        int i1 = esrc[e + 4 + g];
        int i2 = esrc[e + 8 + g];
        int i3 = esrc[e + 12 + g];
        uint4 v0 = *(const uint4*)(hi_prev + (size_t)i0 * 128 + c * 8);
        uint4 v1 = *(const uint4*)(hi_prev + (size_t)i1 * 128 + c * 8);
        uint4 v2 = *(const uint4*)(hi_prev + (size_t)i2 * 128 + c * 8);
        uint4 v3 = *(const uint4*)(hi_prev + (size_t)i3 * 128 + c * 8);
        acc8(s, v0);
        acc8(s, v1);
        acc8(s, v2);
        acc8(s, v3);
    }
    for (; e + 3 < end; e += 4) {
        int i0 = esrc[e + g];
        uint4 v0 = *(const uint4*)(hi_prev + (size_t)i0 * 128 + c * 8);
        acc8(s, v0);
    }
    if (e < end) {  // tail 1..3 rows, predicated per group
        bool act = (e + g) < end;
        int i0 = act ? esrc[e + g] : esrc[e];
        uint4 v0 = *(const uint4*)(hi_prev + (size_t)i0 * 128 + c * 8);
        if (act) acc8(s, v0);
    }

    // fold 4 groups: lanes 0-15 end with totals for cols c*8..c*8+7
#pragma unroll
    for (int k = 0; k < 8; k++) {
        s[k] += __shfl_down(s[k], 32);
        s[k] += __shfl_down(s[k], 16);
    }

    if (g == 0) {
        int d = end - beg;
        float iv = (d > 0) ? 1.0f / (float)d : 0.0f;
        float ep = 1.0f + eps[layer];
        uint4 hv = *(const uint4*)(hi_prev + (size_t)node * 128 + c * 8);
        uint4 lv = *(const uint4*)(lo_prev + (size_t)node * 128 + c * 8);
        unsigned hw[4] = {hv.x, hv.y, hv.z, hv.w};
        unsigned lw[4] = {lv.x, lv.y, lv.z, lv.w};
        float r[8];
#pragma unroll
        for (int k = 0; k < 4; k++) {
            float selfA = bf2f((unsigned short)hw[k]) + bf2f((unsigned short)lw[k]);
            float selfB = bf2f((unsigned short)(hw[k] >> 16)) + bf2f((unsigned short)(lw[k] >> 16));
            r[2 * k] = ep * selfA + s[2 * k] * iv;
            r[2 * k + 1] = ep * selfB + s[2 * k + 1] * iv;
        }
        float* up = u + (size_t)node * 128 + c * 8;
        float4 o0 = {r[0], r[1], r[2], r[3]};
        float4 o1 = {r[4], r[5], r[6], r[7]};
        *(float4*)up = o0;
        *(float4*)(up + 4) = o1;
    }
}

// ---------------- launch ----------------

extern "C" void kernel_launch(void* const* d_in, const int* in_sizes, int n_in,
                              void* d_out, int out_size, void* d_ws, size_t ws_size,
                              hipStream_t stream) {
    const float* X   = (const float*)d_in[0];
    const float* fcW = (const float*)d_in[1];
    const float* fcb = (const float*)d_in[2];
    const float* W   = (const float*)d_in[3];
    const float* b   = (const float*)d_in[4];
    const float* Wl  = (const float*)d_in[5];
    const float* bl  = (const float*)d_in[6];
    const float* eps = (const float*)d_in[7];
    const int* src   = (const int*)d_in[8];
    const int* dst   = (const int*)d_in[9];
    float* out = (float*)d_out;

    // workspace carve (~59 MB); activations single-buffered: agg consumes hi/lo
    // into u, then gemm overwrites hi/lo (stream-ordered, no hazard).
    const size_t NF = (size_t)N_NODES * 128;
    unsigned short* hi_a = (unsigned short*)d_ws;         // NF bf16
    unsigned short* lo_a = hi_a + NF;
    float* u     = (float*)(lo_a + NF);                   // NF fp32
    unsigned short* whi  = (unsigned short*)(u + NF);     // 73728
    unsigned short* wlo  = whi + 73728;                   // 73728
    int* bcnt    = (int*)(wlo + 73728);                   // 1024
    int* boff    = bcnt + 1024;                           // NBUCK+1
    int* cursor  = boff + NBUCK + 1;                      // NBUCK
    int* row_ptr = cursor + NBUCK;                        // N_NODES+1
    int* packed  = row_ptr + N_NODES + 1;                 // N_EDGES
    int* esrc    = packed + N_EDGES;                      // N_EDGES

    const int gemm_blocks = (N_NODES + 63) / 64;        // 782
    const int agg_blocks = (N_NODES * 64 + 255) / 256;  // 12500
    const int prep_blocks = (73728 + 255) / 256;        // 288

    hipMemsetAsync(bcnt, 0, 1024 * sizeof(int), stream);
    fused_hist_prep<<<NSTRIPE + prep_blocks, 256, 0, stream>>>(dst, bcnt, fcW, W, Wl, whi, wlo);
    bucket_scan<<<1, 1024, 0, stream>>>(bcnt, boff, cursor, row_ptr);
    fused_binA_gemm<<<NSTRIPE + gemm_blocks, 256, 0, stream>>>(src, dst, cursor, packed, X, whi,
                                                               wlo, fcb, hi_a, lo_a);
    binB_kernel<<<NBUCK, 256, 0, stream>>>(packed, boff, row_ptr, esrc);

    // 3 hidden GIN layers + last layer, activations in-place
    for (int i = 0; i < 3; i++) {
        agg_kernel<<<agg_blocks, 256, 0, stream>>>(hi_a, lo_a, row_ptr, esrc, eps, i, u);
        gemm_mfma<128, true, false><<<gemm_blocks, 256, 0, stream>>>(
            u, whi + 16384 + (size_t)i * 16384, wlo + 16384 + (size_t)i * 16384,
            b + (size_t)i * 128, hi_a, lo_a, nullptr, N_NODES);
    }
    agg_kernel<<<agg_blocks, 256, 0, stream>>>(hi_a, lo_a, row_ptr, esrc, eps, 3, u);
    gemm_mfma<64, false, true><<<gemm_blocks, 256, 0, stream>>>(u, whi + 65536, wlo + 65536, bl,
                                                                nullptr, nullptr, out, N_NODES);
}